// Round 11
// baseline (1113.001 us; speedup 1.0000x reference)
//
#include <hip/hip_runtime.h>
#include <math.h>

#define H 2048
#define IDIM 5632
#define NE 8
#define TT 2048            // tokens = 2*1024
#define LDW1 (2 * IDIM)    // 11264
#define NK1 (H / 64)       // 32
#define NK2 (IDIM / 64)    // 88

typedef __bf16 bf16x8 __attribute__((ext_vector_type(8)));
typedef float f32x4 __attribute__((ext_vector_type(4)));

__device__ __forceinline__ unsigned short f2bf(float f) {
    unsigned int u = __builtin_bit_cast(unsigned int, f);
    u += 0x7FFFu + ((u >> 16) & 1u);   // round-to-nearest-even
    return (unsigned short)(u >> 16);
}

__device__ __forceinline__ void gload_lds16(const void* g, void* l) {
    __builtin_amdgcn_global_load_lds(
        (const __attribute__((address_space(1))) void*)g,
        (__attribute__((address_space(3))) void*)l, 16, 0, 0);
}

#define PH_OPEN                                         \
    __builtin_amdgcn_s_barrier();                       \
    asm volatile("s_waitcnt lgkmcnt(0)" ::: "memory");  \
    __builtin_amdgcn_sched_barrier(0);                  \
    __builtin_amdgcn_s_setprio(1);

#define CLOSE(V)                                                 \
    __builtin_amdgcn_s_setprio(0);                               \
    __builtin_amdgcn_sched_barrier(0);                           \
    asm volatile("s_waitcnt vmcnt(" V ")" ::: "memory");         \
    __builtin_amdgcn_sched_barrier(0);                           \
    __builtin_amdgcn_s_barrier();                                \
    __builtin_amdgcn_sched_barrier(0);

// ---------------- x (fp32) -> bf16 ----------------
__global__ void cvt_x_kernel(const float* __restrict__ x, unsigned short* __restrict__ xb) {
    int i = blockIdx.x * blockDim.x + threadIdx.x;
    float4 v = reinterpret_cast<const float4*>(x)[i];
    ushort4 o;
    o.x = f2bf(v.x); o.y = f2bf(v.y); o.z = f2bf(v.z); o.w = f2bf(v.w);
    reinterpret_cast<ushort4*>(xb)[i] = o;
}

// ---------------- weights: fp32 [K][N] -> bf16 [N][K] (per matrix) ----------------
__global__ __launch_bounds__(256)
void cvt_w_kernel(const float* __restrict__ src, unsigned short* __restrict__ dst,
                  int K, int N, int tilesPerMat) {
    __shared__ unsigned short tsh[64][72];
    int bid = blockIdx.x;
    int mat = bid / tilesPerMat;
    int tile = bid % tilesPerMat;
    int nbCount = N >> 6;
    int kb = tile / nbCount, nb = tile % nbCount;
    const float* s = src + (size_t)mat * K * N + (size_t)(kb << 6) * N + (nb << 6);
    unsigned short* d = dst + (size_t)mat * K * N + (size_t)(nb << 6) * K + (kb << 6);
    int tid = threadIdx.x;
    int kr = tid >> 4;
    int n4 = (tid & 15) << 2;
#pragma unroll
    for (int p = 0; p < 4; ++p) {
        int k = p * 16 + kr;
        float4 v = *reinterpret_cast<const float4*>(s + (size_t)k * N + n4);
        tsh[n4 + 0][k] = f2bf(v.x);
        tsh[n4 + 1][k] = f2bf(v.y);
        tsh[n4 + 2][k] = f2bf(v.z);
        tsh[n4 + 3][k] = f2bf(v.w);
    }
    __syncthreads();
    int n = tid >> 2;
    int kq = (tid & 3) << 4;
#pragma unroll
    for (int h = 0; h < 2; ++h) {
        uint4 v = *reinterpret_cast<const uint4*>(&tsh[n][kq + h * 8]);
        *reinterpret_cast<uint4*>(d + (size_t)n * K + kq + h * 8) = v;
    }
}

// ---------------- router: fp64 logits, softmax, top-2, lists ----------------
__global__ void router_kernel(const float* __restrict__ x, const float* __restrict__ gw,
                              float* __restrict__ topw, int* __restrict__ cnt,
                              int* __restrict__ list) {
    int t = blockIdx.x;
    int lane = threadIdx.x;
    const float* xt = x + (size_t)t * H;
    double acc[NE];
#pragma unroll
    for (int e = 0; e < NE; ++e) acc[e] = 0.0;
    for (int h = lane; h < H; h += 64) {
        float xv = xt[h];
#pragma unroll
        for (int e = 0; e < NE; ++e) acc[e] += (double)xv * (double)gw[e * H + h];
    }
#pragma unroll
    for (int e = 0; e < NE; ++e) {
#pragma unroll
        for (int off = 32; off > 0; off >>= 1)
            acc[e] += __shfl_xor(acc[e], off, 64);
    }
    if (lane == 0) {
        double mx = acc[0];
#pragma unroll
        for (int e = 1; e < NE; ++e) mx = acc[e] > mx ? acc[e] : mx;
        double ex[NE], s = 0.0;
#pragma unroll
        for (int e = 0; e < NE; ++e) { ex[e] = exp(acc[e] - mx); s += ex[e]; }
        int e0 = 0; double b0 = ex[0];
#pragma unroll
        for (int e = 1; e < NE; ++e) if (ex[e] > b0) { b0 = ex[e]; e0 = e; }
        int e1 = -1; double b1 = -1.0;
#pragma unroll
        for (int e = 0; e < NE; ++e) if (e != e0 && ex[e] > b1) { b1 = ex[e]; e1 = e; }
        float p0 = (float)(b0 / s), p1 = (float)(b1 / s);
        float w0 = p0 / (p0 + p1), w1 = p1 / (p0 + p1);
        topw[t * 2 + 0] = w0;
        topw[t * 2 + 1] = w1;
        int pos0 = atomicAdd(&cnt[e0], 1); list[e0 * TT + pos0] = t * 2 + 0;
        int pos1 = atomicAdd(&cnt[e1], 1); list[e1 * TT + pos1] = t * 2 + 1;
    }
}

// ---------------- tile map (256-row tiles at [20..39]) ----------------
__global__ void setup_kernel(const int* __restrict__ cnt, int* __restrict__ tmap) {
    if (threadIdx.x == 0) {
        int a128 = 0, a256 = 0;
        tmap[0] = 0; tmap[20] = 0;
        for (int g = 0; g < 9; ++g) {
            int rows = (g == 0) ? TT : cnt[g - 1];
            tmap[10 + g] = rows;
            tmap[30 + g] = rows;
            a128 += (rows + 127) >> 7;
            a256 += (rows + 255) >> 8;
            tmap[g + 1] = a128;
            tmap[20 + g + 1] = a256;
        }
        tmap[19] = 0; tmap[39] = 0;
    }
}

// ============ grouped GEMM1: 256x256, BK=64, 4-phase read-once quadrant walk ==========
// Phases: (mh0·BL)(mh0·BH)(mh1·BH)(mh1·BL); bL/bH live across tile (each read once).
// Stage halves one per phase: A0@P1, B0@P2, B1@P3, A1@P4; waits vmcnt 4/4/-/4 steady.
__global__ __launch_bounds__(512)
void gemm1_kernel(const unsigned short* __restrict__ xb,
                  const unsigned short* __restrict__ w1p,
                  const int* __restrict__ tmap,
                  const int* __restrict__ list,
                  unsigned short* __restrict__ actB,
                  unsigned short* __restrict__ actE) {
    __shared__ unsigned short lds_a[2][256 * 64];
    __shared__ unsigned short lds_b[2][256 * 64];
    __shared__ int s_arow[256];
    __shared__ int s_orow[256];
    __shared__ int sh[20];

    int tid = threadIdx.x;
    if (tid < 20) sh[tid] = tmap[20 + tid];
    __syncthreads();
    int bid = blockIdx.x;
    int virt = (bid & 7) * 176 + (bid >> 3);     // 1408 = 8*176; jcols contiguous per XCD
    int jcol = virt >> 5;                        // 0..43
    int rt = virt & 31;
    if (rt >= sh[9]) return;
    int g = 0;
    while (rt >= sh[g + 1]) ++g;
    int rows_g = sh[10 + g];
    int row0 = (rt - sh[g]) * 256;
    int n0a = jcol * 128;

    if (tid < 256) {
        int r = row0 + tid;
        int arow = 0, orow = 0;
        if (r < rows_g) {
            if (g == 0) { arow = r; orow = r; }
            else { int e = list[(g - 1) * TT + r]; arow = e >> 1; orow = e; }
        }
        s_arow[tid] = arow;
        s_orow[tid] = orow;
    }
    __syncthreads();

    const unsigned short* W = w1p + (size_t)g * ((size_t)LDW1 * H);
    unsigned short* actPtr = (g == 0) ? actB : actE;

    // staging sources: chunk = i*512+tid -> lds row = chunk>>3, slot kc = chunk&7
    const unsigned short* asrc[4];
    const unsigned short* bsrc[4];
#pragma unroll
    for (int i = 0; i < 4; ++i) {
        int chunk = i * 512 + tid;
        int sA = chunk >> 3, kc = chunk & 7;
        int grow = ((sA >> 6) & 1) * 128 + ((sA >> 7) & 1) * 64 + (sA & 63);
        asrc[i] = xb + (size_t)s_arow[grow] * H + ((kc ^ (sA & 7)) << 3);
        int w = ((sA >> 7) ? IDIM : 0) + n0a + (((sA >> 5) & 3) << 5) + (sA & 31);
        bsrc[i] = W + (size_t)w * H + ((kc ^ (sA & 7)) << 3);
    }
    int dstoff = (tid >> 6) * 1024;

    auto stA = [&](int half, int kt, int nb) {
#pragma unroll
        for (int ii = 0; ii < 2; ++ii) {
            int i = half * 2 + ii;
            gload_lds16(asrc[i] + kt * 64, (char*)lds_a[nb] + i * 8192 + dstoff);
        }
    };
    auto stB = [&](int half, int kt, int nb) {
#pragma unroll
        for (int ii = 0; ii < 2; ++ii) {
            int i = half * 2 + ii;
            gload_lds16(bsrc[i] + kt * 64, (char*)lds_b[nb] + i * 8192 + dstoff);
        }
    };

    int wave = tid >> 6, lane = tid & 63;
    int wr = wave >> 2, wc = wave & 3;
    int cr = lane & 15, kq = lane >> 4, lxor = lane & 7;

    f32x4 acc[8][4];
#pragma unroll
    for (int fm = 0; fm < 8; ++fm)
#pragma unroll
        for (int fn = 0; fn < 4; ++fn)
            acc[fm][fn] = (f32x4)(0.0f);

    bf16x8 aF[8], bL[4], bH[4];
    auto rdA8 = [&](int buf, int fmh) {
        const char* p = (const char*)lds_a[buf];
#pragma unroll
        for (int kh = 0; kh < 2; ++kh)
#pragma unroll
            for (int i = 0; i < 4; ++i) {
                int sA = fmh * 128 + wr * 64 + i * 16 + cr;
                aF[kh * 4 + i] = *reinterpret_cast<const bf16x8*>(
                    p + sA * 128 + (((kq + kh * 4) ^ lxor) << 4));
            }
    };
    auto rdBL = [&](int buf) {
        const char* p = (const char*)lds_b[buf];
#pragma unroll
        for (int kh = 0; kh < 2; ++kh)
#pragma unroll
            for (int fnl = 0; fnl < 2; ++fnl) {
                int s = wc * 32 + fnl * 16 + cr;
                bL[kh * 2 + fnl] = *reinterpret_cast<const bf16x8*>(
                    p + s * 128 + (((kq + kh * 4) ^ lxor) << 4));
            }
    };
    auto rdBH = [&](int buf) {
        const char* p = (const char*)lds_b[buf];
#pragma unroll
        for (int kh = 0; kh < 2; ++kh)
#pragma unroll
            for (int fnl = 0; fnl < 2; ++fnl) {
                int s = 128 + wc * 32 + fnl * 16 + cr;
                bH[kh * 2 + fnl] = *reinterpret_cast<const bf16x8*>(
                    p + s * 128 + (((kq + kh * 4) ^ lxor) << 4));
            }
    };
    auto MF_L = [&](int fmh) {
#pragma unroll
        for (int kh = 0; kh < 2; ++kh)
#pragma unroll
            for (int fnl = 0; fnl < 2; ++fnl)
#pragma unroll
                for (int i = 0; i < 4; ++i)
                    acc[fmh * 4 + i][fnl] = __builtin_amdgcn_mfma_f32_16x16x32_bf16(
                        aF[kh * 4 + i], bL[kh * 2 + fnl], acc[fmh * 4 + i][fnl], 0, 0, 0);
    };
    auto MF_H = [&](int fmh) {
#pragma unroll
        for (int kh = 0; kh < 2; ++kh)
#pragma unroll
            for (int fnl = 0; fnl < 2; ++fnl)
#pragma unroll
                for (int i = 0; i < 4; ++i)
                    acc[fmh * 4 + i][2 + fnl] = __builtin_amdgcn_mfma_f32_16x16x32_bf16(
                        aF[kh * 4 + i], bH[kh * 2 + fnl], acc[fmh * 4 + i][2 + fnl], 0, 0, 0);
    };

    // Phase order (mh0,BL)(mh0,BH)(mh1,BH)(mh1,BL); reads 12/4/8/0; stages A0/B0/B1/A1.
#define TILE_G(ST, V1, V2, V4)                                   \
    {                                                            \
        rdA8(buf, 0); rdBL(buf);                                 \
        if (ST) stA(0, t + 1, nbuf);                             \
        PH_OPEN; MF_L(0); CLOSE(V1)                              \
        rdBH(buf);                                               \
        if (ST) stB(0, t + 1, nbuf);                             \
        PH_OPEN; MF_H(0); CLOSE(V2)                              \
        rdA8(buf, 1);                                            \
        if (ST) stB(1, t + 1, nbuf);                             \
        PH_OPEN; MF_H(1); CLOSE("63")                            \
        if (ST) stA(1, t + 1, nbuf);                             \
        PH_OPEN; MF_L(1); CLOSE(V4)                              \
    }

    // prologue: stage tile 0 (order A0, B0, B1, A1), drain A0/B0
    stA(0, 0, 0); stB(0, 0, 0); stB(1, 0, 0); stA(1, 0, 0);
    asm volatile("s_waitcnt vmcnt(4)" ::: "memory");
    __builtin_amdgcn_sched_barrier(0);
    __builtin_amdgcn_s_barrier();
    __builtin_amdgcn_sched_barrier(0);

    for (int t = 0; t < NK1 - 1; ++t) {
        int buf = t & 1, nbuf = buf ^ 1;
        TILE_G(true, "4", "4", "4")
    }
    {
        int t = NK1 - 1, buf = t & 1, nbuf = buf ^ 1;
        (void)nbuf;
        TILE_G(false, "2", "0", "63")
    }

    int cq = lane >> 4;
#pragma unroll
    for (int fm = 0; fm < 8; ++fm) {
#pragma unroll
        for (int r = 0; r < 4; ++r) {
            int rloc = wr * 128 + fm * 16 + cq * 4 + r;
            if (row0 + rloc < rows_g) {
                size_t orow = (size_t)s_orow[rloc];
#pragma unroll
                for (int fn = 0; fn < 2; ++fn) {
                    float gv = acc[fm][fn][r];
                    float uv = acc[fm][fn + 2][r];
                    float sv = gv / (1.0f + __expf(-gv));
                    int col = n0a + wc * 32 + fn * 16 + cr;
                    actPtr[orow * IDIM + col] = f2bf(sv * uv);
                }
            }
        }
    }
#undef TILE_G
}

// ============ grouped GEMM2: 256x256, BK=64, same pipeline ============
__global__ __launch_bounds__(512)
void gemm2_kernel(const unsigned short* __restrict__ actB,
                  const unsigned short* __restrict__ actE,
                  const unsigned short* __restrict__ w2p,
                  const int* __restrict__ tmap,
                  const int* __restrict__ list,
                  float* __restrict__ outB,
                  float* __restrict__ yslot) {
    __shared__ unsigned short lds_a[2][256 * 64];
    __shared__ unsigned short lds_b[2][256 * 64];
    __shared__ int s_row[256];
    __shared__ int sh[20];

    int tid = threadIdx.x;
    if (tid < 20) sh[tid] = tmap[20 + tid];
    __syncthreads();
    int bid = blockIdx.x;
    int virt = (bid & 7) * 32 + (bid >> 3);      // 256 = 8*32
    int jcol = virt >> 5;                        // 0..7
    int rt = virt & 31;
    if (rt >= sh[9]) return;
    int g = 0;
    while (rt >= sh[g + 1]) ++g;
    int rows_g = sh[10 + g];
    int row0 = (rt - sh[g]) * 256;
    int n0 = jcol * 256;

    if (tid < 256) {
        int r = row0 + tid;
        int rowi = 0;
        if (r < rows_g) rowi = (g == 0) ? r : list[(g - 1) * TT + r];
        s_row[tid] = rowi;
    }
    __syncthreads();

    const unsigned short* abase = (g == 0) ? actB : actE;
    const unsigned short* W = w2p + (size_t)g * ((size_t)H * IDIM);
    float* obase = (g == 0) ? outB : yslot;

    const unsigned short* asrc[4];
    const unsigned short* bsrc[4];
#pragma unroll
    for (int i = 0; i < 4; ++i) {
        int chunk = i * 512 + tid;
        int sA = chunk >> 3, kc = chunk & 7;
        int grow = ((sA >> 6) & 1) * 128 + ((sA >> 7) & 1) * 64 + (sA & 63);
        asrc[i] = abase + (size_t)s_row[grow] * IDIM + ((kc ^ (sA & 7)) << 3);
        int w = n0 + ((sA >> 5) & 3) * 64 + ((sA >> 7) & 1) * 32 + (sA & 31);
        bsrc[i] = W + (size_t)w * IDIM + ((kc ^ (sA & 7)) << 3);
    }
    int dstoff = (tid >> 6) * 1024;

    auto stA = [&](int half, int kt, int nb) {
#pragma unroll
        for (int ii = 0; ii < 2; ++ii) {
            int i = half * 2 + ii;
            gload_lds16(asrc[i] + kt * 64, (char*)lds_a[nb] + i * 8192 + dstoff);
        }
    };
    auto stB = [&](int half, int kt, int nb) {
#pragma unroll
        for (int ii = 0; ii < 2; ++ii) {
            int i = half * 2 + ii;
            gload_lds16(bsrc[i] + kt * 64, (char*)lds_b[nb] + i * 8192 + dstoff);
        }
    };

    int wave = tid >> 6, lane = tid & 63;
    int wr = wave >> 2, wc = wave & 3;
    int cr = lane & 15, kq = lane >> 4, lxor = lane & 7;

    f32x4 acc[8][4];
#pragma unroll
    for (int fm = 0; fm < 8; ++fm)
#pragma unroll
        for (int fn = 0; fn < 4; ++fn)
            acc[fm][fn] = (f32x4)(0.0f);

    bf16x8 aF[8], bL[4], bH[4];
    auto rdA8 = [&](int buf, int fmh) {
        const char* p = (const char*)lds_a[buf];
#pragma unroll
        for (int kh = 0; kh < 2; ++kh)
#pragma unroll
            for (int i = 0; i < 4; ++i) {
                int sA = fmh * 128 + wr * 64 + i * 16 + cr;
                aF[kh * 4 + i] = *reinterpret_cast<const bf16x8*>(
                    p + sA * 128 + (((kq + kh * 4) ^ lxor) << 4));
            }
    };
    auto rdBL = [&](int buf) {
        const char* p = (const char*)lds_b[buf];
#pragma unroll
        for (int kh = 0; kh < 2; ++kh)
#pragma unroll
            for (int fnl = 0; fnl < 2; ++fnl) {
                int s = wc * 32 + fnl * 16 + cr;
                bL[kh * 2 + fnl] = *reinterpret_cast<const bf16x8*>(
                    p + s * 128 + (((kq + kh * 4) ^ lxor) << 4));
            }
    };
    auto rdBH = [&](int buf) {
        const char* p = (const char*)lds_b[buf];
#pragma unroll
        for (int kh = 0; kh < 2; ++kh)
#pragma unroll
            for (int fnl = 0; fnl < 2; ++fnl) {
                int s = 128 + wc * 32 + fnl * 16 + cr;
                bH[kh * 2 + fnl] = *reinterpret_cast<const bf16x8*>(
                    p + s * 128 + (((kq + kh * 4) ^ lxor) << 4));
            }
    };
    auto MF_L = [&](int fmh) {
#pragma unroll
        for (int kh = 0; kh < 2; ++kh)
#pragma unroll
            for (int fnl = 0; fnl < 2; ++fnl)
#pragma unroll
                for (int i = 0; i < 4; ++i)
                    acc[fmh * 4 + i][fnl] = __builtin_amdgcn_mfma_f32_16x16x32_bf16(
                        aF[kh * 4 + i], bL[kh * 2 + fnl], acc[fmh * 4 + i][fnl], 0, 0, 0);
    };
    auto MF_H = [&](int fmh) {
#pragma unroll
        for (int kh = 0; kh < 2; ++kh)
#pragma unroll
            for (int fnl = 0; fnl < 2; ++fnl)
#pragma unroll
                for (int i = 0; i < 4; ++i)
                    acc[fmh * 4 + i][2 + fnl] = __builtin_amdgcn_mfma_f32_16x16x32_bf16(
                        aF[kh * 4 + i], bH[kh * 2 + fnl], acc[fmh * 4 + i][2 + fnl], 0, 0, 0);
    };

#define TILE_G(ST, V1, V2, V4)                                   \
    {                                                            \
        rdA8(buf, 0); rdBL(buf);                                 \
        if (ST) stA(0, t + 1, nbuf);                             \
        PH_OPEN; MF_L(0); CLOSE(V1)                              \
        rdBH(buf);                                               \
        if (ST) stB(0, t + 1, nbuf);                             \
        PH_OPEN; MF_H(0); CLOSE(V2)                              \
        rdA8(buf, 1);                                            \
        if (ST) stB(1, t + 1, nbuf);                             \
        PH_OPEN; MF_H(1); CLOSE("63")                            \
        if (ST) stA(1, t + 1, nbuf);                             \
        PH_OPEN; MF_L(1); CLOSE(V4)                              \
    }

    stA(0, 0, 0); stB(0, 0, 0); stB(1, 0, 0); stA(1, 0, 0);
    asm volatile("s_waitcnt vmcnt(4)" ::: "memory");
    __builtin_amdgcn_sched_barrier(0);
    __builtin_amdgcn_s_barrier();
    __builtin_amdgcn_sched_barrier(0);

    for (int t = 0; t < NK2 - 1; ++t) {
        int buf = t & 1, nbuf = buf ^ 1;
        TILE_G(true, "4", "4", "4")
    }
    {
        int t = NK2 - 1, buf = t & 1, nbuf = buf ^ 1;
        (void)nbuf;
        TILE_G(false, "2", "0", "63")
    }

    int cq = lane >> 4;
#pragma unroll
    for (int fm = 0; fm < 8; ++fm) {
#pragma unroll
        for (int r = 0; r < 4; ++r) {
            int rloc = wr * 128 + fm * 16 + cq * 4 + r;
            if (row0 + rloc < rows_g) {
                size_t orow = (size_t)s_row[rloc];
#pragma unroll
                for (int fn = 0; fn < 4; ++fn) {
                    int col = n0 + wc * 64 + fn * 16 + cr;
                    obase[orow * H + col] = acc[fm][fn][r];
                }
            }
        }
    }
#undef TILE_G
}

// ---------------- combine: out += w0*y0 + w1*y1 ----------------
__global__ void combine_kernel(float* __restrict__ out, const float* __restrict__ yslot,
                               const float* __restrict__ topw) {
    int i = blockIdx.x * blockDim.x + threadIdx.x;
    int t = i >> 9;
    int c = (i & 511) << 2;
    float w0 = topw[t * 2], w1 = topw[t * 2 + 1];
    float4 y0 = *reinterpret_cast<const float4*>(yslot + ((size_t)(2 * t) * H + c));
    float4 y1 = *reinterpret_cast<const float4*>(yslot + ((size_t)(2 * t + 1) * H + c));
    float4* po = reinterpret_cast<float4*>(out + ((size_t)t * H + c));
    float4 o = *po;
    o.x += w0 * y0.x + w1 * y1.x;
    o.y += w0 * y0.y + w1 * y1.y;
    o.z += w0 * y0.z + w1 * y1.z;
    o.w += w0 * y0.w + w1 * y1.w;
    *po = o;
}

extern "C" void kernel_launch(void* const* d_in, const int* in_sizes, int n_in,
                              void* d_out, int out_size, void* d_ws, size_t ws_size,
                              hipStream_t stream) {
    const float* x   = (const float*)d_in[0];
    const float* gw  = (const float*)d_in[1];
    const float* bgu = (const float*)d_in[2];
    const float* bdn = (const float*)d_in[3];
    const float* egu = (const float*)d_in[4];
    const float* edn = (const float*)d_in[5];
    float* out = (float*)d_out;
    char* ws = (char*)d_ws;

    unsigned short* xb   = (unsigned short*)(ws + 0);
    unsigned short* actB = (unsigned short*)(ws + 8388608);
    unsigned short* actE = (unsigned short*)(ws + 31457280);
    float* yslot         = (float*)(ws + 77594624);
    float* topw          = (float*)(ws + 111149056);
    int* cnt             = (int*)(ws + 111165440);
    int* list            = (int*)(ws + 111165696);
    int* tmap            = (int*)(ws + 111231232);
    unsigned short* w1p  = (unsigned short*)(ws + 111231488);  // 415,236,096 B
    unsigned short* w2p  = (unsigned short*)(ws + 526467584);  // 207,618,048 B

    hipMemsetAsync(cnt, 0, NE * sizeof(int), stream);
    cvt_x_kernel<<<4096, 256, 0, stream>>>(x, xb);
    router_kernel<<<TT, 64, 0, stream>>>(x, gw, topw, cnt, list);
    setup_kernel<<<1, 64, 0, stream>>>(cnt, tmap);

    cvt_w_kernel<<<5632, 256, 0, stream>>>(bgu, w1p, H, LDW1, 5632);
    cvt_w_kernel<<<8 * 5632, 256, 0, stream>>>(egu, w1p + (size_t)LDW1 * H, H, LDW1, 5632);
    cvt_w_kernel<<<2816, 256, 0, stream>>>(bdn, w2p, IDIM, H, 2816);
    cvt_w_kernel<<<8 * 2816, 256, 0, stream>>>(edn, w2p + (size_t)H * IDIM, IDIM, H, 2816);

    gemm1_kernel<<<1408, 512, 0, stream>>>(xb, w1p, tmap, list, actB, actE);
    gemm2_kernel<<<256, 512, 0, stream>>>(actB, actE, w2p, tmap, list, out, yslot);
    combine_kernel<<<4096, 256, 0, stream>>>(out, yslot, topw);
}

// Round 12
// 902.705 us; speedup vs baseline: 1.2330x; 1.2330x over previous
//
#include <hip/hip_runtime.h>
#include <math.h>

#define H 2048
#define IDIM 5632
#define NE 8
#define TT 2048            // tokens = 2*1024
#define LDW1 (2 * IDIM)    // 11264
#define NK1 (H / 64)       // 32
#define NK2 (IDIM / 64)    // 88

typedef __bf16 bf16x8 __attribute__((ext_vector_type(8)));
typedef float f32x4 __attribute__((ext_vector_type(4)));

__device__ __forceinline__ unsigned short f2bf(float f) {
    unsigned int u = __builtin_bit_cast(unsigned int, f);
    u += 0x7FFFu + ((u >> 16) & 1u);   // round-to-nearest-even
    return (unsigned short)(u >> 16);
}

// HW convert: compiler emits v_cvt_pk_bf16_f32 from paired casts (RTNE)
__device__ __forceinline__ unsigned int pk2(float a, float b) {
    __bf16 x = (__bf16)a, y = (__bf16)b;
    unsigned short lo = __builtin_bit_cast(unsigned short, x);
    unsigned short hi = __builtin_bit_cast(unsigned short, y);
    return (unsigned int)lo | ((unsigned int)hi << 16);
}

__device__ __forceinline__ void gload_lds16(const void* g, void* l) {
    __builtin_amdgcn_global_load_lds(
        (const __attribute__((address_space(1))) void*)g,
        (__attribute__((address_space(3))) void*)l, 16, 0, 0);
}

#define PH_OPEN                                         \
    __builtin_amdgcn_s_barrier();                       \
    asm volatile("s_waitcnt lgkmcnt(0)" ::: "memory");  \
    __builtin_amdgcn_sched_barrier(0);                  \
    __builtin_amdgcn_s_setprio(1);
#define PH_CL                                           \
    __builtin_amdgcn_s_setprio(0);                      \
    __builtin_amdgcn_sched_barrier(0);                  \
    __builtin_amdgcn_s_barrier();

// 16 dword loads: rows rlo..rlo+3 x 4 spread cols (static indices only)
#define LDB_HALF(BR, kt, rlo)                                            \
    {                                                                    \
        _Pragma("unroll")                                                \
        for (int r_ = 0; r_ < 4; ++r_) {                                 \
            _Pragma("unroll")                                            \
            for (int j_ = 0; j_ < 4; ++j_)                               \
                BR[(rlo) + r_][j_] =                                     \
                    bp[j_][(size_t)((kt) * 64 + (rlo) + r_) * BST];      \
        }                                                                \
    }
// cvt+pack+swizzled b128 writes, chunks jlo..jlo+1 (conflict-free, r8-verified)
#define WRB_HALF(BR, nb, jlo)                                            \
    {                                                                    \
        char* pbw_ = (char*)lds_b[nb];                                   \
        _Pragma("unroll")                                                \
        for (int j_ = (jlo); j_ < (jlo) + 2; ++j_) {                     \
            uint4 pk_;                                                   \
            pk_.x = pk2(BR[0][j_], BR[1][j_]);                           \
            pk_.y = pk2(BR[2][j_], BR[3][j_]);                           \
            pk_.z = pk2(BR[4][j_], BR[5][j_]);                           \
            pk_.w = pk2(BR[6][j_], BR[7][j_]);                           \
            *reinterpret_cast<uint4*>(pbw_ + bwaddr[j_]) = pk_;          \
        }                                                                \
    }

// 4-phase fold-convert K-tile. BRC holds B(t+1) (write to nbuf); BRN gets B(t+2).
#define TILE_F(T, BRC, BRN, DO_STA, DO_LDB, DO_WR, VB)                   \
    {                                                                    \
        const int buf_ = (T) & 1, nbuf_ = buf_ ^ 1;                      \
        const char* pa_ = (const char*)lds_a[buf_];                      \
        const char* pb_ = (const char*)lds_b[buf_];                      \
        int slot0_ = (kq ^ lxor) << 4;                                   \
        int slot1_ = ((kq + 4) ^ lxor) << 4;                             \
        rdB(bfr, pb_, slot0_);                                           \
        rdA(a0, pa_, slot0_, 0);                                         \
        if (DO_STA) issueA((T) + 1, nbuf_);                              \
        if (DO_LDB) LDB_HALF(BRN, (T) + 2, 0)                            \
        PH_OPEN; mf16(a0, bfr, 0); PH_CL                                 \
        rdA(a1, pa_, slot0_, 1);                                         \
        if (DO_WR) WRB_HALF(BRC, nbuf_, 0)                               \
        PH_OPEN; mf16(a1, bfr, 1); PH_CL                                 \
        rdB(bfr, pb_, slot1_);                                           \
        rdA(a1, pa_, slot1_, 1);                                         \
        if (DO_LDB) LDB_HALF(BRN, (T) + 2, 4)                            \
        PH_OPEN; mf16(a1, bfr, 1); PH_CL                                 \
        rdA(a0, pa_, slot1_, 0);                                         \
        if (DO_WR) WRB_HALF(BRC, nbuf_, 2)                               \
        __builtin_amdgcn_s_barrier();                                    \
        asm volatile("s_waitcnt lgkmcnt(0)" ::: "memory");               \
        __builtin_amdgcn_sched_barrier(0);                               \
        __builtin_amdgcn_s_setprio(1);                                   \
        mf16(a0, bfr, 0);                                                \
        __builtin_amdgcn_s_setprio(0);                                   \
        __builtin_amdgcn_sched_barrier(0);                               \
        asm volatile("s_waitcnt vmcnt(" VB ")" ::: "memory");            \
        __builtin_amdgcn_sched_barrier(0);                               \
        __builtin_amdgcn_s_barrier();                                    \
        __builtin_amdgcn_sched_barrier(0);                               \
    }

// ---------------- x (fp32) -> bf16 ----------------
__global__ void cvt_x_kernel(const float* __restrict__ x, unsigned short* __restrict__ xb) {
    int i = blockIdx.x * blockDim.x + threadIdx.x;
    float4 v = reinterpret_cast<const float4*>(x)[i];
    ushort4 o;
    o.x = f2bf(v.x); o.y = f2bf(v.y); o.z = f2bf(v.z); o.w = f2bf(v.w);
    reinterpret_cast<ushort4*>(xb)[i] = o;
}

// ---------------- router: fp64 logits, softmax, top-2, lists ----------------
__global__ void router_kernel(const float* __restrict__ x, const float* __restrict__ gw,
                              float* __restrict__ topw, int* __restrict__ cnt,
                              int* __restrict__ list) {
    int t = blockIdx.x;
    int lane = threadIdx.x;
    const float* xt = x + (size_t)t * H;
    double acc[NE];
#pragma unroll
    for (int e = 0; e < NE; ++e) acc[e] = 0.0;
    for (int h = lane; h < H; h += 64) {
        float xv = xt[h];
#pragma unroll
        for (int e = 0; e < NE; ++e) acc[e] += (double)xv * (double)gw[e * H + h];
    }
#pragma unroll
    for (int e = 0; e < NE; ++e) {
#pragma unroll
        for (int off = 32; off > 0; off >>= 1)
            acc[e] += __shfl_xor(acc[e], off, 64);
    }
    if (lane == 0) {
        double mx = acc[0];
#pragma unroll
        for (int e = 1; e < NE; ++e) mx = acc[e] > mx ? acc[e] : mx;
        double ex[NE], s = 0.0;
#pragma unroll
        for (int e = 0; e < NE; ++e) { ex[e] = exp(acc[e] - mx); s += ex[e]; }
        int e0 = 0; double b0 = ex[0];
#pragma unroll
        for (int e = 1; e < NE; ++e) if (ex[e] > b0) { b0 = ex[e]; e0 = e; }
        int e1 = -1; double b1 = -1.0;
#pragma unroll
        for (int e = 0; e < NE; ++e) if (e != e0 && ex[e] > b1) { b1 = ex[e]; e1 = e; }
        float p0 = (float)(b0 / s), p1 = (float)(b1 / s);
        float w0 = p0 / (p0 + p1), w1 = p1 / (p0 + p1);
        topw[t * 2 + 0] = w0;
        topw[t * 2 + 1] = w1;
        int pos0 = atomicAdd(&cnt[e0], 1); list[e0 * TT + pos0] = t * 2 + 0;
        int pos1 = atomicAdd(&cnt[e1], 1); list[e1 * TT + pos1] = t * 2 + 1;
    }
}

// ---------------- tile map (256-row tiles at [20..39]) ----------------
__global__ void setup_kernel(const int* __restrict__ cnt, int* __restrict__ tmap) {
    if (threadIdx.x == 0) {
        int a128 = 0, a256 = 0;
        tmap[0] = 0; tmap[20] = 0;
        for (int g = 0; g < 9; ++g) {
            int rows = (g == 0) ? TT : cnt[g - 1];
            tmap[10 + g] = rows;
            tmap[30 + g] = rows;
            a128 += (rows + 127) >> 7;
            a256 += (rows + 255) >> 8;
            tmap[g + 1] = a128;
            tmap[20 + g + 1] = a256;
        }
        tmap[19] = 0; tmap[39] = 0;
    }
}

// ============ grouped GEMM1: 256x256, BK=64, fold-convert, 2-deep B, counted vmcnt ====
__global__ __launch_bounds__(512)
void gemm1_kernel(const unsigned short* __restrict__ xb,
                  const float* __restrict__ base_gu,
                  const float* __restrict__ exp_gu,
                  const int* __restrict__ tmap,
                  const int* __restrict__ list,
                  unsigned short* __restrict__ actB,
                  unsigned short* __restrict__ actE) {
    __shared__ unsigned short lds_a[2][256 * 64];
    __shared__ unsigned short lds_b[2][256 * 64];
    __shared__ int s_arow[256];
    __shared__ int s_orow[256];
    __shared__ int sh[20];

    int tid = threadIdx.x;
    if (tid < 20) sh[tid] = tmap[20 + tid];
    __syncthreads();
    int bid = blockIdx.x;
    int virt = (bid & 7) * 176 + (bid >> 3);     // 1408 = 8*176; jcols contiguous per XCD
    int jcol = virt >> 5;                        // 0..43
    int rt = virt & 31;
    if (rt >= sh[9]) return;
    int g = 0;
    while (rt >= sh[g + 1]) ++g;
    int rows_g = sh[10 + g];
    int row0 = (rt - sh[g]) * 256;
    int n0a = jcol * 128;                        // act-col base

    if (tid < 256) {
        int r = row0 + tid;
        int arow = 0, orow = 0;
        if (r < rows_g) {
            if (g == 0) { arow = r; orow = r; }
            else { int e = list[(g - 1) * TT + r]; arow = e >> 1; orow = e; }
        }
        s_arow[tid] = arow;
        s_orow[tid] = orow;
    }
    __syncthreads();

    const float* W = (g == 0) ? base_gu : (exp_gu + (size_t)(g - 1) * H * LDW1);
    unsigned short* actPtr = (g == 0) ? actB : actE;
    const size_t BST = LDW1;

    // A staging sources (4 gloads/tile; chunk = i*512+tid -> row=chunk>>3, kc=chunk&7)
    const unsigned short* asrc[4];
#pragma unroll
    for (int i = 0; i < 4; ++i) {
        int chunk = i * 512 + tid;
        int rl = chunk >> 3, kc = chunk & 7;
        asrc[i] = xb + (size_t)s_arow[rl] * H + ((kc ^ (rl & 7)) << 3);
    }
    int dstoff = (tid >> 6) * 1024;

    // B fp32 staging: ks = wave (k-rows ks*8..+7), cb = lane; 4 spread cols
    int ks = tid >> 6, cb = tid & 63;
    const float* bp[4];
    int bwaddr[4];
#pragma unroll
    for (int j = 0; j < 4; ++j) {
        int rl = cb + 64 * j;
        int wcol = (((rl >> 5) & 1) ? IDIM : 0) + n0a + ((rl >> 6) << 5) + (rl & 31);
        bp[j] = W + (size_t)(ks * 8) * LDW1 + wcol;
        bwaddr[j] = rl * 128 + ((ks ^ (cb & 7)) << 4);
    }

    auto issueA = [&](int kt, int buf) {
#pragma unroll
        for (int i = 0; i < 4; ++i)
            gload_lds16(asrc[i] + kt * 64, (char*)lds_a[buf] + i * 8192 + dstoff);
    };

    int wave = tid >> 6, lane = tid & 63;
    int wr = wave >> 2, wc = wave & 3;
    int arow0 = wr * 128 + (lane & 15);
    int bcol0 = wc * 64 + (lane & 15);
    int lxor = lane & 7;
    int kq = lane >> 4;

    f32x4 acc[8][4];
#pragma unroll
    for (int fm = 0; fm < 8; ++fm)
#pragma unroll
        for (int fn = 0; fn < 4; ++fn)
            acc[fm][fn] = (f32x4)(0.0f);

    bf16x8 a0[4], a1[4], bfr[4];
    auto rdA = [&](bf16x8* d, const char* pa, int slot, int fmh) {
#pragma unroll
        for (int i = 0; i < 4; ++i)
            d[i] = *reinterpret_cast<const bf16x8*>(pa + (arow0 + fmh * 64 + i * 16) * 128 + slot);
    };
    auto rdB = [&](bf16x8* d, const char* pb, int slot) {
#pragma unroll
        for (int fn = 0; fn < 4; ++fn)
            d[fn] = *reinterpret_cast<const bf16x8*>(pb + (bcol0 + fn * 16) * 128 + slot);
    };
    auto mf16 = [&](bf16x8* af, bf16x8* bf, int fmh) {
#pragma unroll
        for (int fn = 0; fn < 4; ++fn)
#pragma unroll
            for (int i = 0; i < 4; ++i)
                acc[fmh * 4 + i][fn] = __builtin_amdgcn_mfma_f32_16x16x32_bf16(
                    af[i], bf[fn], acc[fmh * 4 + i][fn], 0, 0, 0);
    };

    float brA[8][4], brB[8][4];

    // prologue: A(0)+B(0) staged; B(1) in brA; B(0) via brB
    issueA(0, 0);
    LDB_HALF(brB, 0, 0) LDB_HALF(brB, 0, 4)
    WRB_HALF(brB, 0, 0) WRB_HALF(brB, 0, 2)     // implicit waits drain B(0)+A(0)... A older
    LDB_HALF(brA, 1, 0) LDB_HALF(brA, 1, 4)
    asm volatile("s_waitcnt vmcnt(32) lgkmcnt(0)" ::: "memory");
    __builtin_amdgcn_sched_barrier(0);
    __builtin_amdgcn_s_barrier();
    __builtin_amdgcn_sched_barrier(0);

    for (int t = 0; t + 3 < NK1; t += 2) {
        TILE_F(t, brA, brB, true, true, true, "32")
        TILE_F(t + 1, brB, brA, true, true, true, "32")
    }
    TILE_F(NK1 - 2, brA, brB, true, false, true, "0")
    TILE_F(NK1 - 1, brB, brA, false, false, false, "63")

    int cq = lane >> 4, cr = lane & 15;
#pragma unroll
    for (int fm = 0; fm < 8; ++fm) {
#pragma unroll
        for (int r = 0; r < 4; ++r) {
            int rloc = wr * 128 + fm * 16 + cq * 4 + r;
            if (row0 + rloc < rows_g) {
                size_t orow = (size_t)s_orow[rloc];
#pragma unroll
                for (int fn = 0; fn < 2; ++fn) {
                    float gv = acc[fm][fn][r];
                    float uv = acc[fm][fn + 2][r];
                    float sv = gv / (1.0f + __expf(-gv));
                    int col = n0a + wc * 32 + fn * 16 + cr;
                    actPtr[orow * IDIM + col] = f2bf(sv * uv);
                }
            }
        }
    }
}

// ============ grouped GEMM2: 256x256, BK=64, fold-convert, same schedule ============
__global__ __launch_bounds__(512)
void gemm2_kernel(const unsigned short* __restrict__ actB,
                  const unsigned short* __restrict__ actE,
                  const float* __restrict__ base_dn,
                  const float* __restrict__ exp_dn,
                  const int* __restrict__ tmap,
                  const int* __restrict__ list,
                  float* __restrict__ outB,
                  float* __restrict__ yslot) {
    __shared__ unsigned short lds_a[2][256 * 64];
    __shared__ unsigned short lds_b[2][256 * 64];
    __shared__ int s_row[256];
    __shared__ int sh[20];

    int tid = threadIdx.x;
    if (tid < 20) sh[tid] = tmap[20 + tid];
    __syncthreads();
    int bid = blockIdx.x;
    int virt = (bid & 7) * 32 + (bid >> 3);      // 256 = 8*32; one col-strip per XCD
    int jcol = virt >> 5;                        // 0..7
    int rt = virt & 31;
    if (rt >= sh[9]) return;
    int g = 0;
    while (rt >= sh[g + 1]) ++g;
    int rows_g = sh[10 + g];
    int row0 = (rt - sh[g]) * 256;
    int n0 = jcol * 256;

    if (tid < 256) {
        int r = row0 + tid;
        int rowi = 0;
        if (r < rows_g) rowi = (g == 0) ? r : list[(g - 1) * TT + r];
        s_row[tid] = rowi;
    }
    __syncthreads();

    const unsigned short* abase = (g == 0) ? actB : actE;
    const float* W = (g == 0) ? base_dn : (exp_dn + (size_t)(g - 1) * IDIM * H);
    float* obase = (g == 0) ? outB : yslot;
    const size_t BST = H;

    const unsigned short* asrc[4];
#pragma unroll
    for (int i = 0; i < 4; ++i) {
        int chunk = i * 512 + tid;
        int rl = chunk >> 3, kc = chunk & 7;
        asrc[i] = abase + (size_t)s_row[rl] * IDIM + ((kc ^ (rl & 7)) << 3);
    }
    int dstoff = (tid >> 6) * 1024;

    int ks = tid >> 6, cb = tid & 63;
    const float* bp[4];
    int bwaddr[4];
#pragma unroll
    for (int j = 0; j < 4; ++j) {
        int rl = cb + 64 * j;
        bp[j] = W + (size_t)(ks * 8) * H + n0 + rl;
        bwaddr[j] = rl * 128 + ((ks ^ (cb & 7)) << 4);
    }

    auto issueA = [&](int kt, int buf) {
#pragma unroll
        for (int i = 0; i < 4; ++i)
            gload_lds16(asrc[i] + kt * 64, (char*)lds_a[buf] + i * 8192 + dstoff);
    };

    int wave = tid >> 6, lane = tid & 63;
    int wr = wave >> 2, wc = wave & 3;
    int arow0 = wr * 128 + (lane & 15);
    int bcol0 = wc * 64 + (lane & 15);
    int lxor = lane & 7;
    int kq = lane >> 4;

    f32x4 acc[8][4];
#pragma unroll
    for (int fm = 0; fm < 8; ++fm)
#pragma unroll
        for (int fn = 0; fn < 4; ++fn)
            acc[fm][fn] = (f32x4)(0.0f);

    bf16x8 a0[4], a1[4], bfr[4];
    auto rdA = [&](bf16x8* d, const char* pa, int slot, int fmh) {
#pragma unroll
        for (int i = 0; i < 4; ++i)
            d[i] = *reinterpret_cast<const bf16x8*>(pa + (arow0 + fmh * 64 + i * 16) * 128 + slot);
    };
    auto rdB = [&](bf16x8* d, const char* pb, int slot) {
#pragma unroll
        for (int fn = 0; fn < 4; ++fn)
            d[fn] = *reinterpret_cast<const bf16x8*>(pb + (bcol0 + fn * 16) * 128 + slot);
    };
    auto mf16 = [&](bf16x8* af, bf16x8* bf, int fmh) {
#pragma unroll
        for (int fn = 0; fn < 4; ++fn)
#pragma unroll
            for (int i = 0; i < 4; ++i)
                acc[fmh * 4 + i][fn] = __builtin_amdgcn_mfma_f32_16x16x32_bf16(
                    af[i], bf[fn], acc[fmh * 4 + i][fn], 0, 0, 0);
    };

    float brA[8][4], brB[8][4];

    issueA(0, 0);
    LDB_HALF(brB, 0, 0) LDB_HALF(brB, 0, 4)
    WRB_HALF(brB, 0, 0) WRB_HALF(brB, 0, 2)
    LDB_HALF(brA, 1, 0) LDB_HALF(brA, 1, 4)
    asm volatile("s_waitcnt vmcnt(32) lgkmcnt(0)" ::: "memory");
    __builtin_amdgcn_sched_barrier(0);
    __builtin_amdgcn_s_barrier();
    __builtin_amdgcn_sched_barrier(0);

    for (int t = 0; t + 3 < NK2; t += 2) {
        TILE_F(t, brA, brB, true, true, true, "32")
        TILE_F(t + 1, brB, brA, true, true, true, "32")
    }
    TILE_F(NK2 - 2, brA, brB, true, false, true, "0")
    TILE_F(NK2 - 1, brB, brA, false, false, false, "63")

    int cq = lane >> 4, cr = lane & 15;
#pragma unroll
    for (int fm = 0; fm < 8; ++fm) {
#pragma unroll
        for (int r = 0; r < 4; ++r) {
            int rloc = wr * 128 + fm * 16 + cq * 4 + r;
            if (row0 + rloc < rows_g) {
                size_t orow = (size_t)s_row[rloc];
#pragma unroll
                for (int fn = 0; fn < 4; ++fn) {
                    int col = n0 + wc * 64 + fn * 16 + cr;
                    obase[orow * H + col] = acc[fm][fn][r];
                }
            }
        }
    }
}

// ---------------- combine: out += w0*y0 + w1*y1 ----------------
__global__ void combine_kernel(float* __restrict__ out, const float* __restrict__ yslot,
                               const float* __restrict__ topw) {
    int i = blockIdx.x * blockDim.x + threadIdx.x;
    int t = i >> 9;
    int c = (i & 511) << 2;
    float w0 = topw[t * 2], w1 = topw[t * 2 + 1];
    float4 y0 = *reinterpret_cast<const float4*>(yslot + ((size_t)(2 * t) * H + c));
    float4 y1 = *reinterpret_cast<const float4*>(yslot + ((size_t)(2 * t + 1) * H + c));
    float4* po = reinterpret_cast<float4*>(out + ((size_t)t * H + c));
    float4 o = *po;
    o.x += w0 * y0.x + w1 * y1.x;
    o.y += w0 * y0.y + w1 * y1.y;
    o.z += w0 * y0.z + w1 * y1.z;
    o.w += w0 * y0.w + w1 * y1.w;
    *po = o;
}

extern "C" void kernel_launch(void* const* d_in, const int* in_sizes, int n_in,
                              void* d_out, int out_size, void* d_ws, size_t ws_size,
                              hipStream_t stream) {
    const float* x   = (const float*)d_in[0];
    const float* gw  = (const float*)d_in[1];
    const float* bgu = (const float*)d_in[2];
    const float* bdn = (const float*)d_in[3];
    const float* egu = (const float*)d_in[4];
    const float* edn = (const float*)d_in[5];
    float* out = (float*)d_out;
    char* ws = (char*)d_ws;

    unsigned short* xb   = (unsigned short*)(ws + 0);          //  8,388,608 B
    unsigned short* actB = (unsigned short*)(ws + 8388608);    // 23,068,672 B
    unsigned short* actE = (unsigned short*)(ws + 31457280);   // 46,137,344 B
    float* yslot         = (float*)(ws + 77594624);            // 33,554,432 B
    float* topw          = (float*)(ws + 111149056);
    int* cnt             = (int*)(ws + 111165440);
    int* list            = (int*)(ws + 111165696);
    int* tmap            = (int*)(ws + 111231232);

    hipMemsetAsync(cnt, 0, NE * sizeof(int), stream);
    cvt_x_kernel<<<4096, 256, 0, stream>>>(x, xb);
    router_kernel<<<TT, 64, 0, stream>>>(x, gw, topw, cnt, list);
    setup_kernel<<<1, 64, 0, stream>>>(cnt, tmap);
    // gemm1: 44 col-strips x up-to-32 row-tiles, XCD-pinned
    gemm1_kernel<<<1408, 512, 0, stream>>>(xb, bgu, egu, tmap, list, actB, actE);
    // gemm2: 8 col-strips x up-to-32 row-tiles
    gemm2_kernel<<<256, 512, 0, stream>>>(actB, actE, bdn, edn, tmap, list, out, yslot);
    combine_kernel<<<4096, 256, 0, stream>>>(out, yslot, topw);
}